// Round 5
// baseline (23006.258 us; speedup 1.0000x reference)
//
#include <hip/hip_runtime.h>
#include <hip/hip_bf16.h>
#include <math.h>

#define T_ 128
#define B_ 256
#define BP 512     // 2B (party batch)
#define D_ 1024
#define H_ 150
#define G_ 600     // 4H
#define O_ 300     // 2H
#define KPAD 156   // Whh K padded to mult of 4 (rows 150..155 zero)
#define KCH 39     // KPAD/4 chunks
#define ROWS 16    // batch rows per scan block

typedef float v2f __attribute__((ext_vector_type(2)));
typedef float v4f __attribute__((ext_vector_type(4)));

// ---------------- workspace layout (4-byte words) ----------------
static const size_t INV_OFF   = 0;                                  // int[128*512]
static const size_t WIHT0_OFF = 65536;                              // 4 x 1024*600
static const size_t WIHT1_OFF = WIHT0_OFF + 4ull * 1024 * 600;      // 4 x 300*600
static const size_t WHHT_OFF  = WIHT1_OFF + 4ull * 300 * 600;       // 8 x KPAD*600
static const size_t XW_OFF    = WHHT_OFF + 8ull * KPAD * 600;       // 2 or 4 slots x 32768*600
static const size_t XSLOT     = 32768ull * 600;                     // 19,660,800 words

static size_t hrnn_off(int nslots) { return XW_OFF + (size_t)nslots * XSLOT; }
static size_t hpr_off(int nslots)  { return hrnn_off(nslots) + 32768ull * 300; }
static size_t total_words(int nslots) { return hpr_off(nslots) + 65536ull * 300; }

// ---------------- fast transcendentals ----------------
__device__ __forceinline__ float fsig(float x) {
    return __builtin_amdgcn_rcpf(1.f + __expf(-x));
}
__device__ __forceinline__ float ftanh(float x) {
    float xc = fminf(fmaxf(x, -15.f), 15.f);
    float e = __expf(-2.f * xc);
    return (1.f - e) * __builtin_amdgcn_rcpf(1.f + e);
}

// ---------------- non-temporal helpers (keep streams out of L2) ----------------
__device__ __forceinline__ v2f ldnt2(const float* p) {
    return __builtin_nontemporal_load((const v2f*)p);
}
__device__ __forceinline__ float ldnt1(const float* p) {
    return __builtin_nontemporal_load(p);
}
__device__ __forceinline__ void stnt1(float* p, float v) {
    __builtin_nontemporal_store(v, p);
}
__device__ __forceinline__ void stnt4(float* p, float x, float y, float z, float w) {
    v4f v = {x, y, z, w};
    __builtin_nontemporal_store(v, (v4f*)p);
}

// ---------------- inverse map: (pos p, party row) -> dialogue row or -1 ----------
__global__ void k_pos(const int* __restrict__ qmask, int* __restrict__ inv) {
    int b = threadIdx.x;   // 256 threads, one per batch column
    for (int p = 0; p < T_; ++p) {
        inv[p * BP + b] = -1;
        inv[p * BP + B_ + b] = -1;
    }
    int c0 = 0, c1 = 0;
    for (int t = 0; t < T_; ++t) {
        int s = qmask[(t * B_ + b) * 2 + 1];
        int p = s ? c1++ : c0++;
        inv[p * BP + s * B_ + b] = t * B_ + b;
    }
}

// ---------------- transpose W[g][k] -> WT[k][g], zero-pad rows k in [K,Kpad) -----
__global__ void k_transpose(const float* __restrict__ src, float* __restrict__ dst,
                            int K, int Kpad) {
    int idx = blockIdx.x * 256 + threadIdx.x;
    int total = Kpad * G_;
    if (idx < total) {
        int k = idx / G_, g = idx - k * G_;
        dst[idx] = (k < K) ? src[(size_t)g * K + k] : 0.f;
    }
}

// ---------------- fp32 GEMM: C[M,600] = A[M,K] @ BT[K,600] + bias ----------------
// tile 128(M) x 64(N) x 16(K); 256 threads; 8x4 micro-tile. M % 128 == 0.
__global__ __launch_bounds__(256) void k_gemm(const float* __restrict__ A,
                                              const float* __restrict__ BT,
                                              const float* __restrict__ bias,
                                              float* __restrict__ C,
                                              int M, int K) {
    __shared__ __align__(16) float As[16][136];
    __shared__ __align__(16) float Bs[16][68];
    int n0 = blockIdx.x * 64, m0 = blockIdx.y * 128;
    int tid = threadIdx.x;
    int tx = tid & 15, ty = tid >> 4;
    int ar = tid >> 2, ac = (tid & 3) * 4;
    int kr = tid >> 4, nc = (tid & 15) * 4;
    float acc[8][4];
#pragma unroll
    for (int i = 0; i < 8; ++i)
#pragma unroll
        for (int j = 0; j < 4; ++j) acc[i][j] = 0.f;

    for (int k0 = 0; k0 < K; k0 += 16) {
        bool fullK = (k0 + 16 <= K);
#pragma unroll
        for (int half = 0; half < 2; ++half) {
            int m = m0 + ar + half * 64;
            const float* ap = A + (size_t)m * K + k0 + ac;
            if (fullK) {
                v4f v = *(const v4f*)ap;
                As[ac + 0][ar + half * 64] = v.x;
                As[ac + 1][ar + half * 64] = v.y;
                As[ac + 2][ar + half * 64] = v.z;
                As[ac + 3][ar + half * 64] = v.w;
            } else {
#pragma unroll
                for (int i = 0; i < 4; ++i) {
                    int k = k0 + ac + i;
                    As[ac + i][ar + half * 64] = (k < K) ? ap[i] : 0.f;
                }
            }
        }
        {
            int k = k0 + kr, n = n0 + nc;
            if (fullK && n + 3 < G_) {
                v4f v = *(const v4f*)(BT + (size_t)k * G_ + n);
                Bs[kr][nc + 0] = v.x; Bs[kr][nc + 1] = v.y;
                Bs[kr][nc + 2] = v.z; Bs[kr][nc + 3] = v.w;
            } else {
#pragma unroll
                for (int i = 0; i < 4; ++i) {
                    int nn = n + i;
                    Bs[kr][nc + i] = (k < K && nn < G_) ? BT[(size_t)k * G_ + nn] : 0.f;
                }
            }
        }
        __syncthreads();
#pragma unroll
        for (int kk = 0; kk < 16; ++kk) {
            v4f a0 = *(const v4f*)&As[kk][ty * 8];
            v4f a1 = *(const v4f*)&As[kk][ty * 8 + 4];
            v4f b  = *(const v4f*)&Bs[kk][tx * 4];
            const float* af = (const float*)&a0;
            const float* af2 = (const float*)&a1;
            const float* bf = (const float*)&b;
#pragma unroll
            for (int i = 0; i < 4; ++i)
#pragma unroll
                for (int j = 0; j < 4; ++j) {
                    acc[i][j] += af[i] * bf[j];
                    acc[4 + i][j] += af2[i] * bf[j];
                }
        }
        __syncthreads();
    }
    int n = n0 + tx * 4;
    if (n + 3 < G_) {
        v4f bv = *(const v4f*)(bias + n);
#pragma unroll
        for (int i = 0; i < 8; ++i) {
            int m = m0 + ty * 8 + i;
            stnt4(C + (size_t)m * G_ + n,
                  acc[i][0] + bv.x, acc[i][1] + bv.y,
                  acc[i][2] + bv.z, acc[i][3] + bv.w);   // streaming store
        }
    } else {
#pragma unroll
        for (int i = 0; i < 8; ++i) {
            int m = m0 + ty * 8 + i;
#pragma unroll
            for (int j = 0; j < 4; ++j)
                if (n + j < G_) stnt1(C + (size_t)m * G_ + n + j, acc[i][j] + bias[n + j]);
        }
    }
}

// ---------------- LSTM scan ----------------
struct ScanArgs {
    const float* xw[4];
    const float* whhT[4];   // [KPAD][600]
    const float* bias[4];   // gatherIn padding fallback
    float*       out[4];
    const int*   inv;
    const float* addSrc;
    const float* umask;
    int Bn[4], colOff[4], bwd[4], gIn[4], gOut[4];
    int blkStart[5];
};

__global__ __launch_bounds__(320, 1) void k_scan(ScanArgs args) {
    int bx = blockIdx.x;
    int ci = 0;
#pragma unroll
    for (int i = 1; i < 4; ++i)
        if (bx >= args.blkStart[i]) ci = i;
    const float* xw   = args.xw[ci];
    const float* whh  = args.whhT[ci];
    const float* bias = args.bias[ci];
    float* out        = args.out[ci];
    const int Bn = args.Bn[ci], colOff = args.colOff[ci], bwd = args.bwd[ci];
    const int gIn = args.gIn[ci], gOut = args.gOut[ci];
    int row0 = (bx - args.blkStart[ci]) * ROWS;

    __shared__ __align__(16) float hs[ROWS][KPAD];
    __shared__ __align__(16) float cs[ROWS][152];
    __shared__ __align__(16) float gs[ROWS][608];
    int tid = threadIdx.x;
    for (int i = tid; i < ROWS * KPAD; i += 320) ((float*)hs)[i] = 0.f;
    for (int i = tid; i < ROWS * 152; i += 320) ((float*)cs)[i] = 0.f;
    __syncthreads();

    int pr = tid < 300 ? tid : 299;   // column pair this thread owns (clamped dup)
    const int cp2 = 2 * pr;

    auto loadX = [&](int t, v2f* xb) {
#pragma unroll
        for (int r = 0; r < ROWS; ++r) {
            const float* xr;
            if (gIn) {
                int g = args.inv[t * Bn + row0 + r];
                xr = (g >= 0) ? xw + (size_t)g * G_ : bias;
            } else {
                xr = xw + ((size_t)t * Bn + row0 + r) * G_;
            }
            xb[r] = ldnt2(xr + cp2);   // streaming read: don't evict Whh from L2
        }
    };

    v2f xb[ROWS];
    loadX(bwd ? T_ - 1 : 0, xb);

    for (int s = 0; s < T_; ++s) {
        int t = bwd ? (T_ - 1 - s) : s;
        v2f a[ROWS];
#pragma unroll
        for (int r = 0; r < ROWS; ++r) a[r] = xb[r];
        if (s + 1 < T_) loadX(bwd ? (T_ - 2 - s) : (s + 1), xb);

        // fully-unrolled MAC: gates += h @ WhhT (Whh stays L2-resident)
#pragma unroll
        for (int c = 0; c < KCH; ++c) {
            v2f w0 = *(const v2f*)(whh + (size_t)(c * 4 + 0) * G_ + cp2);
            v2f w1 = *(const v2f*)(whh + (size_t)(c * 4 + 1) * G_ + cp2);
            v2f w2 = *(const v2f*)(whh + (size_t)(c * 4 + 2) * G_ + cp2);
            v2f w3 = *(const v2f*)(whh + (size_t)(c * 4 + 3) * G_ + cp2);
#pragma unroll
            for (int r = 0; r < ROWS; ++r) {
                v4f hv = *(const v4f*)&hs[r][c * 4];   // broadcast b128
                a[r] += w0 * hv.x;
                a[r] += w1 * hv.y;
                a[r] += w2 * hv.z;
                a[r] += w3 * hv.w;
            }
        }
        if (tid < 300) {
#pragma unroll
            for (int r = 0; r < ROWS; ++r) *(v2f*)&gs[r][cp2] = a[r];
        }
        __syncthreads();

        for (int i = tid; i < ROWS * H_; i += 320) {
            int r = i / H_, j = i - r * H_;
            float gi = gs[r][j], gf = gs[r][H_ + j], gg = gs[r][2 * H_ + j], go = gs[r][3 * H_ + j];
            float ii = fsig(gi), ff = fsig(gf), oo = fsig(go);
            float cc = ff * cs[r][j] + ii * ftanh(gg);
            float hh = oo * ftanh(cc);
            cs[r][j] = cc;
            hs[r][j] = hh;
            if (gOut) {
                int g = args.inv[t * Bn + row0 + r];
                if (g >= 0) {
                    size_t o = (size_t)g * O_ + colOff + j;
                    stnt1(out + o, (ldnt1(args.addSrc + o) + hh) * args.umask[g]);
                }
            } else {
                stnt1(out + ((size_t)t * Bn + row0 + r) * O_ + colOff + j, hh);
            }
        }
        __syncthreads();
    }
}

extern "C" void kernel_launch(void* const* d_in, const int* in_sizes, int n_in,
                              void* d_out, int out_size, void* d_ws, size_t ws_size,
                              hipStream_t stream) {
    const float* U        = (const float*)d_in[0];
    const int*   qmask    = (const int*)d_in[1];
    const float* umask    = (const float*)d_in[2];
    const float* rnn_Wih0 = (const float*)d_in[4];
    const float* rnn_Whh0 = (const float*)d_in[5];
    const float* rnn_b0   = (const float*)d_in[6];
    const float* rnn_Wih1 = (const float*)d_in[7];
    const float* rnn_Whh1 = (const float*)d_in[8];
    const float* rnn_b1   = (const float*)d_in[9];
    const float* pr_Wih0  = (const float*)d_in[10];
    const float* pr_Whh0  = (const float*)d_in[11];
    const float* pr_b0    = (const float*)d_in[12];
    const float* pr_Wih1  = (const float*)d_in[13];
    const float* pr_Whh1  = (const float*)d_in[14];
    const float* pr_b1    = (const float*)d_in[15];

    // adaptive layout: 4 xw slots (merged scans) if workspace allows, else 2
    const int nslots = (ws_size >= total_words(4) * 4ull) ? 4 : 2;

    float* ws    = (float*)d_ws;
    int*   inv   = (int*)d_ws + INV_OFF;
    float* wihT0 = ws + WIHT0_OFF;   // slots: rnn-d0, rnn-d1, pr-d0, pr-d1
    float* wihT1 = ws + WIHT1_OFF;
    float* whhT  = ws + WHHT_OFF;    // slots: rnn0 d0,d1; pr0 d0,d1; rnn1 d0,d1; pr1 d0,d1
    float* X0    = ws + XW_OFF;
    float* X1    = X0 + XSLOT;
    float* X2    = (nslots == 4) ? X1 + XSLOT : X0;   // big path only
    float* X3    = (nslots == 4) ? X2 + XSLOT : X1;
    float* h_rnn = ws + hrnn_off(nslots);
    float* h_pr  = ws + hpr_off(nslots);

    const size_t W0S = 1024ull * 600, W1S = 300ull * 600, WHS = (size_t)KPAD * 600;

    k_pos<<<dim3(1), dim3(256), 0, stream>>>(qmask, inv);

    auto TP = [&](const float* src, float* dst, int K, int Kpad) {
        int total = Kpad * G_;
        k_transpose<<<dim3((total + 255) / 256), dim3(256), 0, stream>>>(src, dst, K, Kpad);
    };
    for (int d = 0; d < 2; ++d) {
        TP(rnn_Wih0 + (size_t)d * G_ * D_, wihT0 + (0 + d) * W0S, D_, D_);
        TP(pr_Wih0  + (size_t)d * G_ * D_, wihT0 + (2 + d) * W0S, D_, D_);
        TP(rnn_Wih1 + (size_t)d * G_ * O_, wihT1 + (0 + d) * W1S, O_, O_);
        TP(pr_Wih1  + (size_t)d * G_ * O_, wihT1 + (2 + d) * W1S, O_, O_);
        TP(rnn_Whh0 + (size_t)d * G_ * H_, whhT + (0 + d) * WHS, H_, KPAD);
        TP(pr_Whh0  + (size_t)d * G_ * H_, whhT + (2 + d) * WHS, H_, KPAD);
        TP(rnn_Whh1 + (size_t)d * G_ * H_, whhT + (4 + d) * WHS, H_, KPAD);
        TP(pr_Whh1  + (size_t)d * G_ * H_, whhT + (6 + d) * WHS, H_, KPAD);
    }

    dim3 blk(256), sblk(320);
    dim3 g32k(10, 256);    // M = 32768
    dim3 g64k(10, 512);    // M = 65536
    const int INF = 0x7fffffff;

    ScanArgs z = {};
    auto setCombo = [&](ScanArgs& sa, int i, const float* xw, const float* wh,
                        const float* bi, float* o, int Bn, int co, int bw,
                        int gi, int go) {
        sa.xw[i] = xw; sa.whhT[i] = wh; sa.bias[i] = bi; sa.out[i] = o;
        sa.Bn[i] = Bn; sa.colOff[i] = co; sa.bwd[i] = bw; sa.gIn[i] = gi; sa.gOut[i] = go;
    };

    if (nslots == 4) {
        // ---- layer 0: all four GEMMs, one 96-block scan ----
        k_gemm<<<g32k, blk, 0, stream>>>(U, wihT0 + 0 * W0S, rnn_b0 + 0 * G_, X0, 32768, D_);
        k_gemm<<<g32k, blk, 0, stream>>>(U, wihT0 + 1 * W0S, rnn_b0 + 1 * G_, X1, 32768, D_);
        k_gemm<<<g32k, blk, 0, stream>>>(U, wihT0 + 2 * W0S, pr_b0 + 0 * G_, X2, 32768, D_);
        k_gemm<<<g32k, blk, 0, stream>>>(U, wihT0 + 3 * W0S, pr_b0 + 1 * G_, X3, 32768, D_);
        ScanArgs sa = z;
        sa.inv = inv;
        setCombo(sa, 0, X0, whhT + 0 * WHS, nullptr, h_rnn, B_, 0, 0, 0, 0);
        setCombo(sa, 1, X1, whhT + 1 * WHS, nullptr, h_rnn, B_, H_, 1, 0, 0);
        setCombo(sa, 2, X2, whhT + 2 * WHS, pr_b0 + 0 * G_, h_pr, BP, 0, 0, 1, 0);
        setCombo(sa, 3, X3, whhT + 3 * WHS, pr_b0 + 1 * G_, h_pr, BP, H_, 1, 1, 0);
        sa.blkStart[0] = 0; sa.blkStart[1] = 16; sa.blkStart[2] = 32;
        sa.blkStart[3] = 64; sa.blkStart[4] = 96;
        k_scan<<<dim3(96), sblk, 0, stream>>>(sa);

        // ---- layer 1 rnn GEMMs + pr-d0 GEMM, rnn scan ----
        k_gemm<<<g32k, blk, 0, stream>>>(h_rnn, wihT1 + 0 * W1S, rnn_b1 + 0 * G_, X0, 32768, O_);
        k_gemm<<<g32k, blk, 0, stream>>>(h_rnn, wihT1 + 1 * W1S, rnn_b1 + 1 * G_, X1, 32768, O_);
        k_gemm<<<g64k, blk, 0, stream>>>(h_pr, wihT1 + 2 * W1S, pr_b1 + 0 * G_, X2, 65536, O_);
        ScanArgs sr = z;
        sr.inv = inv;
        setCombo(sr, 0, X0, whhT + 4 * WHS, nullptr, h_rnn, B_, 0, 0, 0, 0);
        setCombo(sr, 1, X1, whhT + 5 * WHS, nullptr, h_rnn, B_, H_, 1, 0, 0);
        sr.blkStart[0] = 0; sr.blkStart[1] = 16; sr.blkStart[2] = INF;
        sr.blkStart[3] = INF; sr.blkStart[4] = 32;
        k_scan<<<dim3(32), sblk, 0, stream>>>(sr);

        // ---- layer 1 pr-d1 GEMM (into freed X0+X1), then 64-block fused scan ----
        k_gemm<<<g64k, blk, 0, stream>>>(h_pr, wihT1 + 3 * W1S, pr_b1 + 1 * G_, X0, 65536, O_);
        ScanArgs sp = z;
        sp.inv = inv; sp.addSrc = h_rnn; sp.umask = umask;
        setCombo(sp, 0, X2, whhT + 6 * WHS, nullptr, (float*)d_out, BP, 0, 0, 0, 1);
        setCombo(sp, 1, X0, whhT + 7 * WHS, nullptr, (float*)d_out, BP, H_, 1, 0, 1);
        sp.blkStart[0] = 0; sp.blkStart[1] = 32; sp.blkStart[2] = INF;
        sp.blkStart[3] = INF; sp.blkStart[4] = 64;
        k_scan<<<dim3(64), sblk, 0, stream>>>(sp);
    } else {
        // ---- small-workspace phased path ----
        for (int d = 0; d < 2; ++d) {
            k_gemm<<<g32k, blk, 0, stream>>>(U, wihT0 + (0 + d) * W0S, rnn_b0 + d * G_, X0, 32768, D_);
            k_gemm<<<g32k, blk, 0, stream>>>(U, wihT0 + (2 + d) * W0S, pr_b0 + d * G_, X1, 32768, D_);
            ScanArgs sa = z;
            sa.inv = inv;
            setCombo(sa, 0, X0, whhT + (0 + d) * WHS, nullptr, h_rnn, B_, d * H_, d, 0, 0);
            setCombo(sa, 1, X1, whhT + (2 + d) * WHS, pr_b0 + d * G_, h_pr, BP, d * H_, d, 1, 0);
            sa.blkStart[0] = 0; sa.blkStart[1] = 16; sa.blkStart[2] = INF;
            sa.blkStart[3] = INF; sa.blkStart[4] = 48;
            k_scan<<<dim3(48), sblk, 0, stream>>>(sa);
        }
        k_gemm<<<g32k, blk, 0, stream>>>(h_rnn, wihT1 + 0 * W1S, rnn_b1 + 0 * G_, X0, 32768, O_);
        k_gemm<<<g32k, blk, 0, stream>>>(h_rnn, wihT1 + 1 * W1S, rnn_b1 + 1 * G_, X1, 32768, O_);
        {
            ScanArgs sr = z;
            sr.inv = inv;
            setCombo(sr, 0, X0, whhT + 4 * WHS, nullptr, h_rnn, B_, 0, 0, 0, 0);
            setCombo(sr, 1, X1, whhT + 5 * WHS, nullptr, h_rnn, B_, H_, 1, 0, 0);
            sr.blkStart[0] = 0; sr.blkStart[1] = 16; sr.blkStart[2] = INF;
            sr.blkStart[3] = INF; sr.blkStart[4] = 32;
            k_scan<<<dim3(32), sblk, 0, stream>>>(sr);
        }
        for (int d = 0; d < 2; ++d) {
            k_gemm<<<g64k, blk, 0, stream>>>(h_pr, wihT1 + (2 + d) * W1S, pr_b1 + d * G_, X0, 65536, O_);
            ScanArgs sp = z;
            sp.inv = inv; sp.addSrc = h_rnn; sp.umask = umask;
            setCombo(sp, 0, X0, whhT + (6 + d) * WHS, nullptr, (float*)d_out, BP, d * H_, d, 0, 1);
            sp.blkStart[0] = 0; sp.blkStart[1] = INF; sp.blkStart[2] = INF;
            sp.blkStart[3] = INF; sp.blkStart[4] = 32;
            k_scan<<<dim3(32), sblk, 0, stream>>>(sp);
        }
    }
}

// Round 6
// 8002.575 us; speedup vs baseline: 2.8749x; 2.8749x over previous
//
#include <hip/hip_runtime.h>
#include <hip/hip_bf16.h>
#include <math.h>

#define T_ 128
#define B_ 256
#define BP 512     // 2B (party batch)
#define D_ 1024
#define H_ 150
#define G_ 600     // 4H
#define O_ 300     // 2H
#define ROWS 16    // batch rows per scan block (one MFMA M-tile)
#define NT_ 38     // n-tiles of 16 covering 600 (608)
#define KT_ 5      // k-tiles of 32 covering 150 (160)
#define KSTR 164   // hs row stride in floats (16B-aligned, 2-way-bank-free frag reads)
#define GST 616    // gs row stride in floats

typedef float v4f    __attribute__((ext_vector_type(4)));
typedef short bf16x8 __attribute__((ext_vector_type(8)));
typedef float f32x4  __attribute__((ext_vector_type(4)));

// ---------------- workspace layout (4-byte words) ----------------
static const size_t INV_OFF   = 0;                                   // int[128*512]
static const size_t WIHT0_OFF = 65536;                               // 4 x 1024*600
static const size_t WIHT1_OFF = WIHT0_OFF + 4ull * 1024 * 600;       // 4 x 300*600
static const size_t WPK_OFF   = WIHT1_OFF + 4ull * 300 * 600;        // 8 combos x NT*KT*2*512 bf16
static const size_t WPK_WORDS = 8ull * NT_ * KT_ * 2 * 512 / 2;      // shorts/2 = 778,240 words
static const size_t XW_OFF    = WPK_OFF + WPK_WORDS;
static const size_t XSLOT     = 32768ull * 600;

static size_t hrnn_off(int nslots) { return XW_OFF + (size_t)nslots * XSLOT; }
static size_t hpr_off(int nslots)  { return hrnn_off(nslots) + 32768ull * 300; }
static size_t total_words(int nslots) { return hpr_off(nslots) + 65536ull * 300; }

// ---------------- fast transcendentals ----------------
__device__ __forceinline__ float fsig(float x) {
    return __builtin_amdgcn_rcpf(1.f + __expf(-x));
}
__device__ __forceinline__ float ftanh(float x) {
    float xc = fminf(fmaxf(x, -15.f), 15.f);
    float e = __expf(-2.f * xc);
    return (1.f - e) * __builtin_amdgcn_rcpf(1.f + e);
}

// ---------------- inverse map: (pos p, party row) -> dialogue row or -1 ----------
__global__ void k_pos(const int* __restrict__ qmask, int* __restrict__ inv) {
    int b = threadIdx.x;
    for (int p = 0; p < T_; ++p) {
        inv[p * BP + b] = -1;
        inv[p * BP + B_ + b] = -1;
    }
    int c0 = 0, c1 = 0;
    for (int t = 0; t < T_; ++t) {
        int s = qmask[(t * B_ + b) * 2 + 1];
        int p = s ? c1++ : c0++;
        inv[p * BP + s * B_ + b] = t * B_ + b;
    }
}

// ---------------- transpose W[g][k] -> WT[k][g] (for GEMM B^T) ----------------
__global__ void k_transpose(const float* __restrict__ src, float* __restrict__ dst,
                            int K) {
    int idx = blockIdx.x * 256 + threadIdx.x;
    int total = K * G_;
    if (idx < total) {
        int k = idx / G_, g = idx - k * G_;
        dst[idx] = src[(size_t)g * K + k];
    }
}

// ---------------- pack Whh[600][150] into MFMA B-fragment layout, split hi/lo ----
// layout: [combo][nt][kt][which(hi/lo)][lane][8]
struct PackArgs { const float* whh[8]; };
__global__ void k_pack(PackArgs pa, unsigned short* __restrict__ wpk) {
    int gid = blockIdx.x * 256 + threadIdx.x;
    int lane = gid & 63;
    int q = gid >> 6;
    int kt = q % KT_; q /= KT_;
    int nt = q % NT_; q /= NT_;
    if (q >= 8) return;
    const float* W = pa.whh[q];     // [600][150] row-major (gate-col major)
    int col = nt * 16 + (lane & 15);
    int kbase = kt * 32 + (lane >> 4) * 8;
    size_t base = ((((size_t)q * NT_ + nt) * KT_ + kt) * 2) * 512 + (size_t)lane * 8;
    for (int j = 0; j < 8; ++j) {
        int k = kbase + j;
        float v = (col < G_ && k < H_) ? W[(size_t)col * H_ + k] : 0.f;
        unsigned u = __float_as_uint(v);
        unsigned short hi = (unsigned short)(u >> 16);
        float hf = __uint_as_float(u & 0xffff0000u);
        unsigned short lo = (unsigned short)(__float_as_uint(v - hf) >> 16);
        wpk[base + j] = hi;
        wpk[base + 512 + j] = lo;
    }
}

// ---------------- fp32 GEMM: C[M,600] = A[M,K] @ BT[K,600] + bias ----------------
__global__ __launch_bounds__(256) void k_gemm(const float* __restrict__ A,
                                              const float* __restrict__ BT,
                                              const float* __restrict__ bias,
                                              float* __restrict__ C,
                                              int M, int K) {
    __shared__ __align__(16) float As[16][136];
    __shared__ __align__(16) float Bs[16][68];
    int n0 = blockIdx.x * 64, m0 = blockIdx.y * 128;
    int tid = threadIdx.x;
    int tx = tid & 15, ty = tid >> 4;
    int ar = tid >> 2, ac = (tid & 3) * 4;
    int kr = tid >> 4, nc = (tid & 15) * 4;
    float acc[8][4];
#pragma unroll
    for (int i = 0; i < 8; ++i)
#pragma unroll
        for (int j = 0; j < 4; ++j) acc[i][j] = 0.f;

    for (int k0 = 0; k0 < K; k0 += 16) {
        bool fullK = (k0 + 16 <= K);
#pragma unroll
        for (int half = 0; half < 2; ++half) {
            int m = m0 + ar + half * 64;
            const float* ap = A + (size_t)m * K + k0 + ac;
            if (fullK) {
                v4f v = *(const v4f*)ap;
                As[ac + 0][ar + half * 64] = v.x;
                As[ac + 1][ar + half * 64] = v.y;
                As[ac + 2][ar + half * 64] = v.z;
                As[ac + 3][ar + half * 64] = v.w;
            } else {
#pragma unroll
                for (int i = 0; i < 4; ++i) {
                    int k = k0 + ac + i;
                    As[ac + i][ar + half * 64] = (k < K) ? ap[i] : 0.f;
                }
            }
        }
        {
            int k = k0 + kr, n = n0 + nc;
            if (fullK && n + 3 < G_) {
                v4f v = *(const v4f*)(BT + (size_t)k * G_ + n);
                Bs[kr][nc + 0] = v.x; Bs[kr][nc + 1] = v.y;
                Bs[kr][nc + 2] = v.z; Bs[kr][nc + 3] = v.w;
            } else {
#pragma unroll
                for (int i = 0; i < 4; ++i) {
                    int nn = n + i;
                    Bs[kr][nc + i] = (k < K && nn < G_) ? BT[(size_t)k * G_ + nn] : 0.f;
                }
            }
        }
        __syncthreads();
#pragma unroll
        for (int kk = 0; kk < 16; ++kk) {
            v4f a0 = *(const v4f*)&As[kk][ty * 8];
            v4f a1 = *(const v4f*)&As[kk][ty * 8 + 4];
            v4f b  = *(const v4f*)&Bs[kk][tx * 4];
            const float* af = (const float*)&a0;
            const float* af2 = (const float*)&a1;
            const float* bf = (const float*)&b;
#pragma unroll
            for (int i = 0; i < 4; ++i)
#pragma unroll
                for (int j = 0; j < 4; ++j) {
                    acc[i][j] += af[i] * bf[j];
                    acc[4 + i][j] += af2[i] * bf[j];
                }
        }
        __syncthreads();
    }
    int n = n0 + tx * 4;
    if (n + 3 < G_) {
        v4f bv = *(const v4f*)(bias + n);
#pragma unroll
        for (int i = 0; i < 8; ++i) {
            int m = m0 + ty * 8 + i;
            v4f o = {acc[i][0] + bv.x, acc[i][1] + bv.y, acc[i][2] + bv.z, acc[i][3] + bv.w};
            *(v4f*)(C + (size_t)m * G_ + n) = o;
        }
    } else {
#pragma unroll
        for (int i = 0; i < 8; ++i) {
            int m = m0 + ty * 8 + i;
#pragma unroll
            for (int j = 0; j < 4; ++j)
                if (n + j < G_) C[(size_t)m * G_ + n + j] = acc[i][j] + bias[n + j];
        }
    }
}

// ---------------- MFMA LSTM scan: 16 rows/block, split-bf16 emulated fp32 --------
struct Combo {
    const float* xw;
    const unsigned short* wpk;   // packed B fragments [NT][KT][2][64][8]
    const float* bias;           // gatherIn padding fallback
    float* out;
    int Bn, colOff, bwd, gIn, gOut;
};
struct ScanArgs {
    Combo c[4];
    const int* inv;
    const float* addSrc;
    const float* umask;
    int blkStart[5];
};

__global__ __launch_bounds__(256) void k_scan(ScanArgs args) {
    int bx = blockIdx.x, ci = 0;
#pragma unroll
    for (int i = 1; i < 4; ++i)
        if (bx >= args.blkStart[i]) ci = i;
    Combo cb = args.c[ci];
    int row0 = (bx - args.blkStart[ci]) * ROWS;

    __shared__ __align__(16) float hs[ROWS * KSTR];
    __shared__ float cs[ROWS * 152];
    __shared__ float gs[ROWS * GST];
    int tid = threadIdx.x;
    int lane = tid & 63, wv = tid >> 6;
    int col16 = lane & 15, quad = lane >> 4;
    for (int i = tid; i < ROWS * KSTR; i += 256) hs[i] = 0.f;
    for (int i = tid; i < ROWS * 152; i += 256) cs[i] = 0.f;
    __syncthreads();

    // update-phase element ownership: i = tid + it*256 over [0, 16*160)
    int er[10], ej[10];
#pragma unroll
    for (int it = 0; it < 10; ++it) {
        int i = tid + it * 256;
        er[it] = i / 160;
        ej[it] = i - er[it] * 160;
    }

    for (int s = 0; s < T_; ++s) {
        int t = cb.bwd ? (T_ - 1 - s) : s;

        // ---- prefetch xw (consumed after MFMA phase) ----
        float xi[10], xf_[10], xg[10], xo[10];
#pragma unroll
        for (int it = 0; it < 10; ++it) {
            int r = er[it], j = ej[it];
            const float* xr;
            if (cb.gIn) {
                int g = args.inv[t * cb.Bn + row0 + r];
                xr = (g >= 0) ? cb.xw + (size_t)g * G_ : cb.bias;
            } else {
                xr = cb.xw + ((size_t)t * cb.Bn + row0 + r) * G_;
            }
            bool act = (j < H_);
            xi[it]  = act ? xr[j] : 0.f;
            xf_[it] = act ? xr[H_ + j] : 0.f;
            xg[it]  = act ? xr[2 * H_ + j] : 0.f;
            xo[it]  = act ? xr[3 * H_ + j] : 0.f;
        }

        // ---- A fragments (h) from LDS, split hi/lo bf16 ----
        bf16x8 ahi[KT_], alo[KT_];
#pragma unroll
        for (int kt = 0; kt < KT_; ++kt) {
            const float* hp = &hs[col16 * KSTR + kt * 32 + quad * 8];
#pragma unroll
            for (int j = 0; j < 8; ++j) {
                float v = hp[j];
                unsigned u = __float_as_uint(v);
                ahi[kt][j] = (short)(u >> 16);
                float hf = __uint_as_float(u & 0xffff0000u);
                alo[kt][j] = (short)(__float_as_uint(v - hf) >> 16);
            }
        }

        // ---- MFMA: gates_h = h @ WhhT, emulated fp32 via 3x bf16 ----
        for (int nt = wv; nt < NT_; nt += 4) {
            f32x4 acc = {0.f, 0.f, 0.f, 0.f};
            const bf16x8* bp = (const bf16x8*)cb.wpk + ((size_t)nt * KT_) * 2 * 64 + lane;
#pragma unroll
            for (int kt = 0; kt < KT_; ++kt) {
                bf16x8 bhi = bp[0];
                bf16x8 blo = bp[64];
                bp += 128;
                acc = __builtin_amdgcn_mfma_f32_16x16x32_bf16(ahi[kt], bhi, acc, 0, 0, 0);
                acc = __builtin_amdgcn_mfma_f32_16x16x32_bf16(ahi[kt], blo, acc, 0, 0, 0);
                acc = __builtin_amdgcn_mfma_f32_16x16x32_bf16(alo[kt], bhi, acc, 0, 0, 0);
            }
#pragma unroll
            for (int p = 0; p < 4; ++p)
                gs[(quad * 4 + p) * GST + nt * 16 + col16] = acc[p];
        }
        __syncthreads();

        // ---- gate combine + state update + output ----
#pragma unroll
        for (int it = 0; it < 10; ++it) {
            int r = er[it], j = ej[it];
            if (j < H_) {
                float gi = gs[r * GST + j] + xi[it];
                float gf = gs[r * GST + H_ + j] + xf_[it];
                float gg = gs[r * GST + 2 * H_ + j] + xg[it];
                float go = gs[r * GST + 3 * H_ + j] + xo[it];
                float ii = fsig(gi), ff = fsig(gf), oo = fsig(go);
                float cc = ff * cs[r * 152 + j] + ii * ftanh(gg);
                float hh = oo * ftanh(cc);
                cs[r * 152 + j] = cc;
                hs[r * KSTR + j] = hh;
                if (cb.gOut) {
                    int g = args.inv[t * cb.Bn + row0 + r];
                    if (g >= 0) {
                        size_t o = (size_t)g * O_ + cb.colOff + j;
                        cb.out[o] = (args.addSrc[o] + hh) * args.umask[g];
                    }
                } else {
                    cb.out[((size_t)t * cb.Bn + row0 + r) * O_ + cb.colOff + j] = hh;
                }
            }
        }
        __syncthreads();
    }
}

extern "C" void kernel_launch(void* const* d_in, const int* in_sizes, int n_in,
                              void* d_out, int out_size, void* d_ws, size_t ws_size,
                              hipStream_t stream) {
    const float* U        = (const float*)d_in[0];
    const int*   qmask    = (const int*)d_in[1];
    const float* umask    = (const float*)d_in[2];
    const float* rnn_Wih0 = (const float*)d_in[4];
    const float* rnn_Whh0 = (const float*)d_in[5];
    const float* rnn_b0   = (const float*)d_in[6];
    const float* rnn_Wih1 = (const float*)d_in[7];
    const float* rnn_Whh1 = (const float*)d_in[8];
    const float* rnn_b1   = (const float*)d_in[9];
    const float* pr_Wih0  = (const float*)d_in[10];
    const float* pr_Whh0  = (const float*)d_in[11];
    const float* pr_b0    = (const float*)d_in[12];
    const float* pr_Wih1  = (const float*)d_in[13];
    const float* pr_Whh1  = (const float*)d_in[14];
    const float* pr_b1    = (const float*)d_in[15];

    const int nslots = (ws_size >= total_words(4) * 4ull) ? 4 : 2;

    float* ws    = (float*)d_ws;
    int*   inv   = (int*)d_ws + INV_OFF;
    float* wihT0 = ws + WIHT0_OFF;
    float* wihT1 = ws + WIHT1_OFF;
    unsigned short* wpk = (unsigned short*)(ws + WPK_OFF);
    float* X0    = ws + XW_OFF;
    float* X1    = X0 + XSLOT;
    float* X2    = (nslots == 4) ? X1 + XSLOT : X0;
    float* X3    = (nslots == 4) ? X2 + XSLOT : X1;
    float* h_rnn = ws + hrnn_off(nslots);
    float* h_pr  = ws + hpr_off(nslots);

    const size_t W0S = 1024ull * 600, W1S = 300ull * 600;
    const size_t WPS = (size_t)NT_ * KT_ * 2 * 512;   // shorts per combo

    k_pos<<<dim3(1), dim3(256), 0, stream>>>(qmask, inv);

    auto TP = [&](const float* src, float* dst, int K) {
        int total = K * G_;
        k_transpose<<<dim3((total + 255) / 256), dim3(256), 0, stream>>>(src, dst, K);
    };
    for (int d = 0; d < 2; ++d) {
        TP(rnn_Wih0 + (size_t)d * G_ * D_, wihT0 + (0 + d) * W0S, D_);
        TP(pr_Wih0  + (size_t)d * G_ * D_, wihT0 + (2 + d) * W0S, D_);
        TP(rnn_Wih1 + (size_t)d * G_ * O_, wihT1 + (0 + d) * W1S, O_);
        TP(pr_Wih1  + (size_t)d * G_ * O_, wihT1 + (2 + d) * W1S, O_);
    }

    // pack all 8 Whh into MFMA B-fragment hi/lo layout
    PackArgs pa;
    for (int d = 0; d < 2; ++d) {
        pa.whh[0 + d] = rnn_Whh0 + (size_t)d * G_ * H_;
        pa.whh[2 + d] = pr_Whh0  + (size_t)d * G_ * H_;
        pa.whh[4 + d] = rnn_Whh1 + (size_t)d * G_ * H_;
        pa.whh[6 + d] = pr_Whh1  + (size_t)d * G_ * H_;
    }
    {
        int lanes = 8 * NT_ * KT_ * 64;
        k_pack<<<dim3((lanes + 255) / 256), dim3(256), 0, stream>>>(pa, wpk);
    }

    dim3 blk(256);
    dim3 g32k(10, 256);    // M = 32768
    dim3 g64k(10, 512);    // M = 65536
    const int INF = 0x7fffffff;

    ScanArgs z = {};
    auto setCombo = [&](ScanArgs& sa, int i, const float* xw, int wslot,
                        const float* bi, float* o, int Bn, int co, int bw,
                        int gi, int go) {
        sa.c[i].xw = xw; sa.c[i].wpk = wpk + (size_t)wslot * WPS;
        sa.c[i].bias = bi; sa.c[i].out = o;
        sa.c[i].Bn = Bn; sa.c[i].colOff = co; sa.c[i].bwd = bw;
        sa.c[i].gIn = gi; sa.c[i].gOut = go;
    };

    if (nslots == 4) {
        // ---- layer 0: four GEMMs, one 96-block scan ----
        k_gemm<<<g32k, blk, 0, stream>>>(U, wihT0 + 0 * W0S, rnn_b0 + 0 * G_, X0, 32768, D_);
        k_gemm<<<g32k, blk, 0, stream>>>(U, wihT0 + 1 * W0S, rnn_b0 + 1 * G_, X1, 32768, D_);
        k_gemm<<<g32k, blk, 0, stream>>>(U, wihT0 + 2 * W0S, pr_b0 + 0 * G_, X2, 32768, D_);
        k_gemm<<<g32k, blk, 0, stream>>>(U, wihT0 + 3 * W0S, pr_b0 + 1 * G_, X3, 32768, D_);
        ScanArgs sa = z;
        sa.inv = inv;
        setCombo(sa, 0, X0, 0, nullptr, h_rnn, B_, 0, 0, 0, 0);
        setCombo(sa, 1, X1, 1, nullptr, h_rnn, B_, H_, 1, 0, 0);
        setCombo(sa, 2, X2, 2, pr_b0 + 0 * G_, h_pr, BP, 0, 0, 1, 0);
        setCombo(sa, 3, X3, 3, pr_b0 + 1 * G_, h_pr, BP, H_, 1, 1, 0);
        sa.blkStart[0] = 0; sa.blkStart[1] = 16; sa.blkStart[2] = 32;
        sa.blkStart[3] = 64; sa.blkStart[4] = 96;
        k_scan<<<dim3(96), blk, 0, stream>>>(sa);

        // ---- layer 1 rnn GEMMs + pr-d0 GEMM, rnn scan ----
        k_gemm<<<g32k, blk, 0, stream>>>(h_rnn, wihT1 + 0 * W1S, rnn_b1 + 0 * G_, X0, 32768, O_);
        k_gemm<<<g32k, blk, 0, stream>>>(h_rnn, wihT1 + 1 * W1S, rnn_b1 + 1 * G_, X1, 32768, O_);
        k_gemm<<<g64k, blk, 0, stream>>>(h_pr, wihT1 + 2 * W1S, pr_b1 + 0 * G_, X2, 65536, O_);
        ScanArgs sr = z;
        sr.inv = inv;
        setCombo(sr, 0, X0, 4, nullptr, h_rnn, B_, 0, 0, 0, 0);
        setCombo(sr, 1, X1, 5, nullptr, h_rnn, B_, H_, 1, 0, 0);
        sr.blkStart[0] = 0; sr.blkStart[1] = 16; sr.blkStart[2] = INF;
        sr.blkStart[3] = INF; sr.blkStart[4] = 32;
        k_scan<<<dim3(32), blk, 0, stream>>>(sr);

        // ---- layer 1 pr-d1 GEMM (into freed X0+X1), fused final scan ----
        k_gemm<<<g64k, blk, 0, stream>>>(h_pr, wihT1 + 3 * W1S, pr_b1 + 1 * G_, X0, 65536, O_);
        ScanArgs sp = z;
        sp.inv = inv; sp.addSrc = h_rnn; sp.umask = umask;
        setCombo(sp, 0, X2, 6, nullptr, (float*)d_out, BP, 0, 0, 0, 1);
        setCombo(sp, 1, X0, 7, nullptr, (float*)d_out, BP, H_, 1, 0, 1);
        sp.blkStart[0] = 0; sp.blkStart[1] = 32; sp.blkStart[2] = INF;
        sp.blkStart[3] = INF; sp.blkStart[4] = 64;
        k_scan<<<dim3(64), blk, 0, stream>>>(sp);
    } else {
        // ---- small-workspace phased path ----
        for (int d = 0; d < 2; ++d) {
            k_gemm<<<g32k, blk, 0, stream>>>(U, wihT0 + (0 + d) * W0S, rnn_b0 + d * G_, X0, 32768, D_);
            k_gemm<<<g32k, blk, 0, stream>>>(U, wihT0 + (2 + d) * W0S, pr_b0 + d * G_, X1, 32768, D_);
            ScanArgs sa = z;
            sa.inv = inv;
            setCombo(sa, 0, X0, 0 + d, nullptr, h_rnn, B_, d * H_, d, 0, 0);
            setCombo(sa, 1, X1, 2 + d, pr_b0 + d * G_, h_pr, BP, d * H_, d, 1, 0);
            sa.blkStart[0] = 0; sa.blkStart[1] = 16; sa.blkStart[2] = INF;
            sa.blkStart[3] = INF; sa.blkStart[4] = 48;
            k_scan<<<dim3(48), blk, 0, stream>>>(sa);
        }
        k_gemm<<<g32k, blk, 0, stream>>>(h_rnn, wihT1 + 0 * W1S, rnn_b1 + 0 * G_, X0, 32768, O_);
        k_gemm<<<g32k, blk, 0, stream>>>(h_rnn, wihT1 + 1 * W1S, rnn_b1 + 1 * G_, X1, 32768, O_);
        {
            ScanArgs sr = z;
            sr.inv = inv;
            setCombo(sr, 0, X0, 4, nullptr, h_rnn, B_, 0, 0, 0, 0);
            setCombo(sr, 1, X1, 5, nullptr, h_rnn, B_, H_, 1, 0, 0);
            sr.blkStart[0] = 0; sr.blkStart[1] = 16; sr.blkStart[2] = INF;
            sr.blkStart[3] = INF; sr.blkStart[4] = 32;
            k_scan<<<dim3(32), blk, 0, stream>>>(sr);
        }
        for (int d = 0; d < 2; ++d) {
            k_gemm<<<g64k, blk, 0, stream>>>(h_pr, wihT1 + (2 + d) * W1S, pr_b1 + d * G_, X0, 65536, O_);
            ScanArgs sp = z;
            sp.inv = inv; sp.addSrc = h_rnn; sp.umask = umask;
            setCombo(sp, 0, X0, 6 + d, nullptr, (float*)d_out, BP, d * H_, d, 0, 1);
            sp.blkStart[0] = 0; sp.blkStart[1] = INF; sp.blkStart[2] = INF;
            sp.blkStart[3] = INF; sp.blkStart[4] = 32;
            k_scan<<<dim3(32), blk, 0, stream>>>(sp);
        }
    }
}